// Round 7
// baseline (411.930 us; speedup 1.0000x reference)
//
#include <hip/hip_runtime.h>

// CoL: out[p] = sum_{q in 3x3} W[q-p] * L[bin(x_q), bin(x_p)] * x_q
// B=32 C=64 H=128 W=128, L is 5x5, zero pad, bin(x)=clamp((int)(x*5),0,4).
//
// R9 design (per-wave gather pipeline): R2/R4/R7/R8 all land ~91-105us =
// 2.1x the LDS-gather floor (44.5us) with NO pipe saturated and the time
// insensitive to occupancy (R7 1.6 w/SIMD vs R8 3.2 w/SIMD: 98.7 vs 93.6)
// and to reg budget (44..128 VGPR: same). Per-SIMD issue work is ~37k of
// 223k cyc -> waves sit in lgkmcnt waits: the compiler register-minimizes
// (VGPR 48!) into short ds_read->wait->fma cells, exposing ~120cyc LDS
// latency per cell, identically in every wave.
// Fix: depth-1 slab pipeline PER WAVE. Each output row = 3 slabs of
// 24 gathers + 24 fmas; slab s+1's gathers are issued BEFORE slab s's
// fmas, in regions pinned by sched_barrier(0) (compiler cannot
// re-serialize; guide rule #18). Two named lw buffers alternate (all
// literal indices - R5 scratch lesson). Next row's global load issues
// ~2 slabs before QPACK consumes it (hides L2/L3 latency).
//  - rolling 3-row x 10-col window, 1 row/step, 8 steps (R8, kept).
//  - bins packed b*20 per byte, literal BFE unpack (R8, kept).
//  - WL[9][25] = W*L in LDS: 25-dword sub-tables span 25 distinct banks,
//    same-address lanes broadcast -> conflict-free (measured 0).

namespace {
constexpr int H  = 128;
constexpr int WD = 128;
constexpr int PLANES = 32 * 64;          // B*C = 2048 blocks (1 per plane)
constexpr int PX = 8;                    // pixels per row per thread
constexpr int THREADS = 256;             // 16 col-strips x 16 row-walkers
}

__global__ __launch_bounds__(THREADS, 4) void col_kernel(
    const float* __restrict__ x, const float* __restrict__ Wf,
    const float* __restrict__ Lf, float* __restrict__ out)
{
    __shared__ float WL[9 * 25];         // WL[(dr*3+dw)*25 + bq*5 + bp]
    const int t = threadIdx.x;
    if (t < 225) WL[t] = Wf[t / 25] * Lf[t % 25];
    __syncthreads();

    const int col0 = (t & 15) * PX;
    const int r0   = (t >> 4) * 8;       // first output row of this walker

    const float* xp = x + (size_t)blockIdx.x * (H * WD);
    float* opb      = out + (size_t)blockIdx.x * (H * WD);
    const char* wlb = (const char*)WL;

    float win[3][PX + 2];                // rolling 3-row window
    int   pk[3][3];                      // packed bins: b*20 per byte
    float lw0[24], lw1[24];              // pipelined gather slabs
    float acc[PX];
    int   bp4[PX];                       // center bins * 4 (byte offset)

#define SB __builtin_amdgcn_sched_barrier(0);

// ---- all-literal-index helpers (keep mem2reg alive; R5 lesson) ---------
#define LOAD_ROW(S, RR) {                                                 \
    const int _rr = (RR);                                                 \
    if (_rr >= 0 && _rr < H) {                                            \
        const float* _rp = xp + _rr * WD + col0;                          \
        const float4 _c0 = *(const float4*)_rp;      /* 16B aligned */    \
        const float4 _c1 = *(const float4*)(_rp + 4);                     \
        win[S][0] = (col0 > 0) ? _rp[-1] : 0.f;                           \
        win[S][1] = _c0.x; win[S][2] = _c0.y;                             \
        win[S][3] = _c0.z; win[S][4] = _c0.w;                             \
        win[S][5] = _c1.x; win[S][6] = _c1.y;                             \
        win[S][7] = _c1.z; win[S][8] = _c1.w;                             \
        win[S][9] = (col0 < WD - PX) ? _rp[PX] : 0.f;                     \
    } else {                                                              \
        _Pragma("unroll")                                                 \
        for (int _j = 0; _j < PX + 2; ++_j) win[S][_j] = 0.f;             \
    } }

// quantize row S, pack b*20 (0..80) into bytes: 3 regs per row
#define QPACK(S) {                                                        \
    int _b[PX + 2];                                                       \
    _Pragma("unroll")                                                     \
    for (int _j = 0; _j < PX + 2; ++_j) {                                 \
        int _v = (int)(win[S][_j] * 5.0f);    /* x>=0: trunc==floor */    \
        _v = (_v > 4) ? 4 : _v;                                           \
        _b[_j] = _v * 20;                                                 \
    }                                                                     \
    pk[S][0] = _b[0] | (_b[1] << 8) | (_b[2] << 16) | (_b[3] << 24);      \
    pk[S][1] = _b[4] | (_b[5] << 8) | (_b[6] << 16) | (_b[7] << 24);      \
    pk[S][2] = _b[8] | (_b[9] << 8); }

// byte-field extract, S and J compile-time literals -> one v_bfe
#define BF(S, J) ((pk[S][(J) >> 2] >> (8 * ((J) & 3))) & 0xff)

// bp4 for NEXT step's center slot B: b*4 == (b20*52429)>>18 exactly
#define BP4(B) {                                                          \
    _Pragma("unroll")                                                     \
    for (int _i = 0; _i < PX; ++_i)                                       \
        bp4[_i] = (BF(B, _i + 1) * 52429) >> 18; }

// gather slab: 24 table reads for q-row in slot QS at window offset DR
#define GS(LW, QS, DR) {                                                  \
    _Pragma("unroll")                                                     \
    for (int _dw = 0; _dw < 3; ++_dw) {                                   \
        _Pragma("unroll")                                                 \
        for (int _i = 0; _i < PX; ++_i)                                   \
            LW[_dw * 8 + _i] = *(const float*)(wlb +                      \
                (BF(QS, _i + _dw) + bp4[_i] + ((DR) * 3 + _dw) * 100));   \
    } }

// fma slab: consume a gather slab
#define FS(LW, QS) {                                                      \
    _Pragma("unroll")                                                     \
    for (int _dw = 0; _dw < 3; ++_dw) {                                   \
        _Pragma("unroll")                                                 \
        for (int _i = 0; _i < PX; ++_i)                                   \
            acc[_i] = fmaf(LW[_dw * 8 + _i], win[QS][_i + _dw], acc[_i]); \
    } }

#define ZACC {                                                            \
    _Pragma("unroll")                                                     \
    for (int _i = 0; _i < PX; ++_i) acc[_i] = 0.f; }

#define STORE(R) {                                                        \
    float* _op = opb + (R) * WD + col0;                                   \
    *(float4*)_op       = make_float4(acc[0], acc[1], acc[2], acc[3]);    \
    *(float4*)(_op + 4) = make_float4(acc[4], acc[5], acc[6], acc[7]);    \
    }

// One step: out row R; slots PA,PB,PC hold rows R-1,R,R+1; on entry X
// already holds this step's dr=0 slab and bp4 is this step's centers.
// Loads row R+2 into PA (freed after FS(X,PA)); pre-issues next step's
// dr=0 slab into Y with the NEXT bp4.  Fences pin {G}|{F} regions.
#define STEP(PA, PB, PC, R, X, Y)                                         \
    GS(Y, PB, 1) SB                                                       \
    ZACC FS(X, PA) LOAD_ROW(PA, (R) + 2) SB                               \
    GS(X, PC, 2) SB                                                       \
    FS(Y, PB) QPACK(PA) BP4(PC) SB                                        \
    GS(Y, PB, 0) SB                                                       \
    FS(X, PC) STORE(R)

// Final step: no prefetch, no next-slab pre-issue.
#define STEPLAST(PA, PB, PC, R, X, Y)                                     \
    GS(Y, PB, 1) SB                                                       \
    ZACC FS(X, PA) SB                                                     \
    GS(X, PC, 2) SB                                                       \
    FS(Y, PB) SB                                                          \
    FS(X, PC) STORE(R)

    // ---- prologue: rows r0-1, r0, r0+1 into slots 0,1,2 ---------------
    LOAD_ROW(0, r0 - 1) QPACK(0)
    LOAD_ROW(1, r0 + 0) QPACK(1)
    LOAD_ROW(2, r0 + 1) QPACK(2)
    BP4(1)                               // centers of out row r0
    GS(lw0, 0, 0) SB                     // step 0's dr=0 slab

    // ---- 8 steps; roles rotate period 3, buffers alternate ------------
    STEP(0, 1, 2, r0 + 0, lw0, lw1)
    STEP(1, 2, 0, r0 + 1, lw1, lw0)
    STEP(2, 0, 1, r0 + 2, lw0, lw1)
    STEP(0, 1, 2, r0 + 3, lw1, lw0)
    STEP(1, 2, 0, r0 + 4, lw0, lw1)
    STEP(2, 0, 1, r0 + 5, lw1, lw0)
    STEP(0, 1, 2, r0 + 6, lw0, lw1)
    STEPLAST(1, 2, 0, r0 + 7, lw1, lw0)

#undef SB
#undef LOAD_ROW
#undef QPACK
#undef BF
#undef BP4
#undef GS
#undef FS
#undef ZACC
#undef STORE
#undef STEP
#undef STEPLAST
}

extern "C" void kernel_launch(void* const* d_in, const int* in_sizes, int n_in,
                              void* d_out, int out_size, void* d_ws, size_t ws_size,
                              hipStream_t stream) {
    const float* x  = (const float*)d_in[0];   // input_tensor (B,C,H,W) fp32
    const float* Wf = (const float*)d_in[1];   // W (1,3,3) fp32
    const float* Lf = (const float*)d_in[2];   // L (5,5) fp32
    float* out = (float*)d_out;

    col_kernel<<<dim3(PLANES), dim3(THREADS), 0, stream>>>(x, Wf, Lf, out);
}

// Round 10
// 278.076 us; speedup vs baseline: 1.4814x; 1.4814x over previous
//
#include <hip/hip_runtime.h>

// CoL: out[p] = sum_{q in 3x3} W[q-p] * L[bin(x_q), bin(x_p)] * x_q
// B=32 C=64 H=128 W=128, L is 5x5, zero pad, bin(x)=clamp((int)(x*5),0,4).
//
// R12 = R10/R11 resubmitted (two consecutive broker failures, no
// compile/run evidence either time; R4->R5 precedent says these are
// infra flakes).
//
// R10 design (dual-stream latency overlap):
// Evidence R2..R9: clean kernels all ~91-105us = 2.1x the 44.5us LDS-gather
// floor; insensitive to occupancy and reg budget; per-CU audit shows LDS
// (48%) + VALU (24%) + global (~5%) ~= 100% SERIALIZED: waves convoy
// through gather-burst -> lgkmcnt drain -> fma-burst in lockstep, pipes
// never overlap. Forced schedules (sched_barrier, runtime-indexed bufs)
// all ended in scratch (R5/R9: WRITE 339/664MB).
// Fix: each thread computes the SAME (row, 4px strip) in TWO PLANES
// (A: plane p, B: plane p+1024). Two independent dep chains, slabs
// ping-ponged in source order with a single lw buffer per stream:
//   GA0 GB0 FA0 GA1 FB0 GB1 FA1 GA2 FB1 GB2 FA2 FB2
// WAR on lwA forces GA1 after FA0 by DATAFLOW (no fences) -> while A's
// slab drains the LDS pipe, B's gathers issue and A's fmas retire. The
// wave covers its own latency; pipe stays fed.
//  - 4 px/thread/stream keeps live state ~105 VGPR (fits 128 @ 4 w/SIMD).
//  - stateless blocks (R4 style, best measured): 3-row window reloaded,
//    L3 absorbs refetch (R4: FETCH 68MB).
//  - bins packed b*20 per byte (2 ints/row), literal BFE unpack.
//  - bp4 = b*4 via exact magic ((b20*52429)>>18).
//  - WL[9][25] = W*L in LDS; 25-dword sub-tables span 25 banks,
//    same-address lanes broadcast; <=2-way aliasing is free (measured 0).
//  - all literal indices via macros (R5/R9 scratch lesson).

namespace {
constexpr int H  = 128;
constexpr int WD = 128;
constexpr int PPT = 4;                   // px per thread per stream
constexpr int THREADS = 256;             // 32 col-strips x 8 rows
constexpr int ROWS_PB = 8;               // rows per block
constexpr int TILES = H / ROWS_PB;       // 16
constexpr int PAIRS = 1024;              // plane pairs (p, p+1024)
}

__global__ __launch_bounds__(THREADS, 4) void col_kernel(
    const float* __restrict__ x, const float* __restrict__ Wf,
    const float* __restrict__ Lf, float* __restrict__ out)
{
    __shared__ float WL[9 * 25];         // WL[(dr*3+dw)*25 + bq*5 + bp]
    const int t = threadIdx.x;
    if (t < 225) WL[t] = Wf[t / 25] * Lf[t % 25];
    __syncthreads();

    const int cs  = (t & 31) * PPT;              // col start 0..124
    const int row = (blockIdx.x & 15) * ROWS_PB + (t >> 5);
    const int pA  = blockIdx.x >> 4;             // 0..1023

    const float* xa = x + (size_t)pA * (H * WD);
    const float* xb = x + (size_t)(pA + PAIRS) * (H * WD);
    float* oa = out + (size_t)pA * (H * WD) + row * WD + cs;
    float* ob = out + (size_t)(pA + PAIRS) * (H * WD) + row * WD + cs;
    const char* wlb = (const char*)WL;

    // per-stream state, all literal-indexed
    float winA[3][PPT + 2], winB[3][PPT + 2];
    int   pkA[3][2],        pkB[3][2];   // bins packed: b*20 per byte
    int   bp4A[PPT],        bp4B[PPT];   // center bin*4 (byte offset)
    float lwA[12],          lwB[12];     // one gather slab per stream
    float accA[PPT],        accB[PPT];

// ---- all-literal helpers (R5/R9 lesson: no fences, no runtime idx) -----
#define LOAD_ROW(WR, XP, RR) {                                            \
    const int _rr = (RR);                                                 \
    if (_rr >= 0 && _rr < H) {                                            \
        const float* _rp = (XP) + _rr * WD + cs;                          \
        const float4 _c = *(const float4*)_rp;       /* 16B aligned */    \
        WR[0] = (cs > 0) ? _rp[-1] : 0.f;                                 \
        WR[1] = _c.x; WR[2] = _c.y; WR[3] = _c.z; WR[4] = _c.w;           \
        WR[5] = (cs < WD - PPT) ? _rp[PPT] : 0.f;                         \
    } else {                                                              \
        _Pragma("unroll")                                                 \
        for (int _j = 0; _j < PPT + 2; ++_j) WR[_j] = 0.f;                \
    } }

// quantize 6 window values of row WR, pack b*20 bytes into PK[0..1]
#define QPACK(WR, PK) {                                                   \
    int _b[PPT + 2];                                                      \
    _Pragma("unroll")                                                     \
    for (int _j = 0; _j < PPT + 2; ++_j) {                                \
        int _v = (int)(WR[_j] * 5.0f);        /* x>=0: trunc==floor */    \
        _v = (_v > 4) ? 4 : _v;                                           \
        _b[_j] = _v * 20;                                                 \
    }                                                                     \
    PK[0] = _b[0] | (_b[1] << 8) | (_b[2] << 16) | (_b[3] << 24);         \
    PK[1] = _b[4] | (_b[5] << 8); }

// byte-field extract; PK, J compile-time-shaped -> one v_bfe
#define BF(PK, J) ((PK[(J) >> 2] >> (8 * ((J) & 3))) & 0xff)

// center bins (window row 1, cols 1..4) as b*4 byte offsets
#define BP4(PK1, BP) {                                                    \
    _Pragma("unroll")                                                     \
    for (int _i = 0; _i < PPT; ++_i)                                      \
        BP[_i] = (BF(PK1, _i + 1) * 52429) >> 18;    /* b20 -> b4 */ }

// gather slab: 12 table reads for window row DR (literal)
#define GS(LW, PK, BP, DR) {                                              \
    _Pragma("unroll")                                                     \
    for (int _dw = 0; _dw < 3; ++_dw) {                                   \
        _Pragma("unroll")                                                 \
        for (int _i = 0; _i < PPT; ++_i)                                  \
            LW[_dw * PPT + _i] = *(const float*)(wlb +                    \
                (BF(PK[DR], _i + _dw) + BP[_i] + ((DR) * 3 + _dw) * 100));\
    } }

// fma slab: consume LW against window row DR
#define FS(LW, WIN, ACC, DR) {                                            \
    _Pragma("unroll")                                                     \
    for (int _dw = 0; _dw < 3; ++_dw) {                                   \
        _Pragma("unroll")                                                 \
        for (int _i = 0; _i < PPT; ++_i)                                  \
            ACC[_i] = fmaf(LW[_dw * PPT + _i], WIN[DR][_i + _dw],         \
                           ACC[_i]);                                      \
    } }

    // ---- prologue: issue all 6 row loads, then quantize ----------------
    LOAD_ROW(winA[0], xa, row - 1)
    LOAD_ROW(winA[1], xa, row + 0)
    LOAD_ROW(winA[2], xa, row + 1)
    LOAD_ROW(winB[0], xb, row - 1)
    LOAD_ROW(winB[1], xb, row + 0)
    LOAD_ROW(winB[2], xb, row + 1)

    QPACK(winA[0], pkA[0]) QPACK(winA[1], pkA[1]) QPACK(winA[2], pkA[2])
    QPACK(winB[0], pkB[0]) QPACK(winB[1], pkB[1]) QPACK(winB[2], pkB[2])
    BP4(pkA[1], bp4A)
    BP4(pkB[1], bp4B)

    #pragma unroll
    for (int i = 0; i < PPT; ++i) { accA[i] = 0.f; accB[i] = 0.f; }

    // ---- ping-pong slab pipeline (dataflow-enforced interleave) --------
    GS(lwA, pkA, bp4A, 0)
    GS(lwB, pkB, bp4B, 0)
    FS(lwA, winA, accA, 0)
    GS(lwA, pkA, bp4A, 1)
    FS(lwB, winB, accB, 0)
    GS(lwB, pkB, bp4B, 1)
    FS(lwA, winA, accA, 1)
    GS(lwA, pkA, bp4A, 2)
    FS(lwB, winB, accB, 1)
    GS(lwB, pkB, bp4B, 2)
    FS(lwA, winA, accA, 2)
    FS(lwB, winB, accB, 2)

    // ---- stores --------------------------------------------------------
    *(float4*)oa = make_float4(accA[0], accA[1], accA[2], accA[3]);
    *(float4*)ob = make_float4(accB[0], accB[1], accB[2], accB[3]);

#undef LOAD_ROW
#undef QPACK
#undef BF
#undef BP4
#undef GS
#undef FS
}

extern "C" void kernel_launch(void* const* d_in, const int* in_sizes, int n_in,
                              void* d_out, int out_size, void* d_ws, size_t ws_size,
                              hipStream_t stream) {
    const float* x  = (const float*)d_in[0];   // input_tensor (B,C,H,W) fp32
    const float* Wf = (const float*)d_in[1];   // W (1,3,3) fp32
    const float* Lf = (const float*)d_in[2];   // L (5,5) fp32
    float* out = (float*)d_out;

    col_kernel<<<dim3(PAIRS * TILES), dim3(THREADS), 0, stream>>>(x, Wf, Lf, out);
}